// Round 26
// baseline (95.121 us; speedup 1.0000x reference)
//
#include <hip/hip_runtime.h>
#include <stdint.h>

#define B_ 4
#define N_ 2048
#define M_ 2048
#define F_ 512
#define H_ 8
#define D_ 64

typedef __bf16 bf16x8 __attribute__((ext_vector_type(8)));
typedef float f32x4 __attribute__((ext_vector_type(4)));
typedef float f32x16 __attribute__((ext_vector_type(16)));

typedef const __attribute__((address_space(1))) uint32_t* gas_ptr;
typedef __attribute__((address_space(3))) uint32_t* las_ptr;

__device__ inline ushort f32_bf16(float f) {
    union { float f; uint32_t u; } v; v.f = f;
    uint32_t r = v.u + 0x7FFFu + ((v.u >> 16) & 1u);
    return (ushort)(r >> 16);
}

// ---------------- Fused LN (18432 rows) + weight transpose (1024 tile-blocks) -----
__global__ __launch_bounds__(128) void prep_kernel(
    const float* __restrict__ x, const float* __restrict__ ctx, const float* __restrict__ pos,
    const float* __restrict__ lnw, const float* __restrict__ lnb,
    const float* __restrict__ lncw, const float* __restrict__ lncb,
    const float* __restrict__ Wq, const float* __restrict__ Wk,
    const float* __restrict__ Wv, const float* __restrict__ Wo,
    ushort* __restrict__ xn, ushort* __restrict__ kn, ushort* __restrict__ cn,
    ushort* __restrict__ WqT, ushort* __restrict__ WkT,
    ushort* __restrict__ WvT, ushort* __restrict__ WoT)
{
    __shared__ float red[4];
    __shared__ float tile[32][33];
    int r = blockIdx.x;
    int tid = threadIdx.x;

    if (r < B_ * N_ + M_ + B_ * M_) {
        // ---- LayerNorm branch
        const float* src; ushort* dst; const float* w; const float* bp;
        if (r < B_ * N_) {
            src = x + (size_t)r * F_; dst = xn + (size_t)r * F_; w = lnw; bp = lnb;
        } else if (r < B_ * N_ + M_) {
            int rr = r - B_ * N_;
            src = pos + (size_t)rr * F_; dst = kn + (size_t)rr * F_; w = lnw; bp = lnb;
        } else {
            int rr = r - (B_ * N_ + M_);
            src = ctx + (size_t)rr * F_; dst = cn + (size_t)rr * F_; w = lncw; bp = lncb;
        }
        int wave = tid >> 6, lane = tid & 63;
        float4 v = reinterpret_cast<const float4*>(src)[tid];
        float s = v.x + v.y + v.z + v.w;
        float sq = v.x * v.x + v.y * v.y + v.z * v.z + v.w * v.w;
        #pragma unroll
        for (int mask = 1; mask < 64; mask <<= 1) {
            s += __shfl_xor(s, mask, 64);
            sq += __shfl_xor(sq, mask, 64);
        }
        if (lane == 0) { red[wave * 2] = s; red[wave * 2 + 1] = sq; }
        __syncthreads();
        float S = red[0] + red[2], SQ = red[1] + red[3];
        float mean = S * (1.0f / F_);
        float var = SQ * (1.0f / F_) - mean * mean;
        float rstd = rsqrtf(var + 1e-5f);
        float4 wv = reinterpret_cast<const float4*>(w)[tid];
        float4 bv = reinterpret_cast<const float4*>(bp)[tid];
        ushort4 o;
        o.x = f32_bf16((v.x - mean) * rstd * wv.x + bv.x);
        o.y = f32_bf16((v.y - mean) * rstd * wv.y + bv.y);
        o.z = f32_bf16((v.z - mean) * rstd * wv.z + bv.z);
        o.w = f32_bf16((v.w - mean) * rstd * wv.w + bv.w);
        reinterpret_cast<ushort4*>(dst)[tid] = o;
        return;
    }

    // ---- weight transpose branch: 1024 blocks of 32x32 tiles (128 threads)
    int wblk = r - (B_ * N_ + M_ + B_ * M_);
    const float* W; ushort* WT;
    switch (wblk >> 8) {
        case 0: W = Wq; WT = WqT; break;
        case 1: W = Wk; WT = WkT; break;
        case 2: W = Wv; WT = WvT; break;
        default: W = Wo; WT = WoT; break;
    }
    int ti = wblk & 255;
    int n0 = (ti & 15) * 32, k0 = (ti >> 4) * 32;
    int tx = tid & 31, ty = tid >> 5;          // 32 x 4
    #pragma unroll
    for (int j = 0; j < 8; ++j)
        tile[ty + j * 4][tx] = W[(size_t)(k0 + ty + j * 4) * F_ + n0 + tx];
    __syncthreads();
    #pragma unroll
    for (int j = 0; j < 8; ++j)
        WT[(size_t)(n0 + ty + j * 4) * F_ + k0 + tx] = f32_bf16(tile[tx][ty + j * 4]);
}

// ---------------- Shared GEMM body: 2-phase staged global_load_lds + XOR swizzle --
// T3-minimum pipeline: STAGE(t+1) issued BEFORE compute(t) into the other LDS
// buffer; one barrier per K-step. Prefetch loads overlap the compute phase and
// are drained by the iteration-end barrier.
// mode: 0 = bf16 row-major PRE-SCALED by 0.125*log2e (Q projection),
//       1 = f32 row-major + bias,
//       2 = K fragment-pack (kF[h][t][fk][lane][8], fk=s*8+ds*2+ab),
//       3 = V fragment-pack (vF[bh][t][fv][lane][8], fv=hh*8+s*4+s_)
#define GSTAGE(BSEL, KOFS) do {                                                \
    _Pragma("unroll")                                                          \
    for (int j_ = 0; j_ < 4; ++j_) {                                           \
        __builtin_amdgcn_global_load_lds(                                      \
            (gas_ptr)(const void*)(agp + (KOFS) + j_ * 8 * F_),                \
            (las_ptr)(void*)&As[BSEL][wv * 32 + j_ * 8][0], 16, 0, 0);         \
        __builtin_amdgcn_global_load_lds(                                      \
            (gas_ptr)(const void*)(bgp + (KOFS) + j_ * 8 * F_),                \
            (las_ptr)(void*)&Bs[BSEL][wv * 32 + j_ * 8][0], 16, 0, 0);         \
    }                                                                          \
} while (0)

__device__ __forceinline__ void gemm_body(
    const ushort* __restrict__ A, const ushort* __restrict__ BT,
    const float* __restrict__ bias, void* __restrict__ Cout,
    int mode, int bx, int by)
{
    __shared__ ushort As[2][128][64];
    __shared__ ushort Bs[2][128][64];
    int tid = threadIdx.x;
    int row0 = by * 128, col0 = bx * 128;
    int wv = tid >> 6, lane = tid & 63;
    int wm = wv >> 1, wn = wv & 1;
    f32x4 acc[4][4] = {};

    const int lrow8 = lane >> 3;
    const int chs = ((lane & 7) ^ (lrow8 & 7)) * 8;
    const ushort* agp = A + (size_t)(row0 + wv * 32 + lrow8) * F_ + chs;
    const ushort* bgp = BT + (size_t)(col0 + wv * 32 + lrow8) * F_ + chs;

    GSTAGE(0, 0);
    __syncthreads();
    int cur = 0;
    #pragma unroll 1
    for (int t = 0; t < 8; ++t) {
        if (t < 7) GSTAGE(cur ^ 1, (t + 1) * 64);   // prefetch next tile
        #pragma unroll
        for (int kt = 0; kt < 2; ++kt) {
            int lrow = lane & 15;
            int ch = ((kt * 4 + (lane >> 4)) ^ (lane & 7)) * 8;
            bf16x8 af[4], bfr[4];
            #pragma unroll
            for (int mt = 0; mt < 4; ++mt)
                af[mt] = *reinterpret_cast<const bf16x8*>(&As[cur][wm * 64 + mt * 16 + lrow][ch]);
            #pragma unroll
            for (int nt = 0; nt < 4; ++nt)
                bfr[nt] = *reinterpret_cast<const bf16x8*>(&Bs[cur][wn * 64 + nt * 16 + lrow][ch]);
            #pragma unroll
            for (int mt = 0; mt < 4; ++mt)
                #pragma unroll
                for (int nt = 0; nt < 4; ++nt)
                    acc[mt][nt] = __builtin_amdgcn_mfma_f32_16x16x32_bf16(
                        af[mt], bfr[nt], acc[mt][nt], 0, 0, 0);
        }
        __syncthreads();   // drains prefetch (landed under compute) + read-safety
        cur ^= 1;
    }

    int lr4 = (lane >> 4) * 4, lc = lane & 15;
    #pragma unroll
    for (int mt = 0; mt < 4; ++mt) {
        #pragma unroll
        for (int nt = 0; nt < 4; ++nt) {
            int ccol = col0 + wn * 64 + nt * 16 + lc;
            float bv = (mode == 1) ? bias[ccol] : 0.0f;
            #pragma unroll
            for (int j = 0; j < 4; ++j) {
                int crow = row0 + wm * 64 + mt * 16 + lr4 + j;
                float val = acc[mt][nt][j] + bv;
                if (mode == 1) {
                    reinterpret_cast<float*>(Cout)[(size_t)crow * F_ + ccol] = val;
                } else if (mode == 0) {
                    // fold softmax scale*log2(e) into Q at pack time
                    reinterpret_cast<ushort*>(Cout)[(size_t)crow * F_ + ccol] =
                        f32_bf16(val * 0.18033688f);
                } else if (mode == 2) {
                    int h = ccol >> 6, t = crow >> 7, s = (crow >> 6) & 1;
                    int ab = (crow >> 5) & 1, l31 = crow & 31;
                    int ds = (ccol >> 4) & 3, g2 = (ccol >> 3) & 1, e = ccol & 7;
                    size_t addr = (((size_t)(h * 16 + t) * 16 + s * 8 + ds * 2 + ab) * 64
                                   + g2 * 32 + l31) * 8 + e;
                    reinterpret_cast<ushort*>(Cout)[addr] = f32_bf16(val);
                } else {
                    int b2 = crow >> 11, m = crow & 2047;
                    int h = ccol >> 6, d = ccol & 63;
                    int bh = b2 * 8 + h, hh = d >> 5, l31 = d & 31;
                    int t = m >> 7, s = (m >> 6) & 1, s_ = (m >> 4) & 3;
                    int g2 = (m >> 3) & 1, i = m & 7;
                    size_t addr = (((size_t)(bh * 16 + t) * 16 + hh * 8 + s * 4 + s_) * 64
                                   + g2 * 32 + l31) * 8 + i;
                    reinterpret_cast<ushort*>(Cout)[addr] = f32_bf16(val);
                }
            }
        }
    }
}

// Merged Q/K/V projection: 576 blocks (Q:0-255, K:256-319, V:320-575).
__global__ __launch_bounds__(256) void qkv_gemm_kernel(
    const ushort* __restrict__ xn, const ushort* __restrict__ kn,
    const ushort* __restrict__ cn,
    const ushort* __restrict__ WqT, const ushort* __restrict__ WkT,
    const ushort* __restrict__ WvT,
    ushort* __restrict__ qb, ushort* __restrict__ kF, ushort* __restrict__ vF)
{
    int bid = blockIdx.x;
    if (bid < 256) {
        gemm_body(xn, WqT, nullptr, (void*)qb, 0, bid & 3, bid >> 2);
    } else if (bid < 320) {
        int t = bid - 256;
        gemm_body(kn, WkT, nullptr, (void*)kF, 2, t & 3, t >> 2);
    } else {
        int t = bid - 320;
        gemm_body(cn, WvT, nullptr, (void*)vF, 3, t & 3, t >> 2);
    }
}

__global__ __launch_bounds__(256) void out_gemm_kernel(
    const ushort* __restrict__ A, const ushort* __restrict__ WoT,
    const float* __restrict__ bias, float* __restrict__ out)
{
    gemm_body(A, WoT, bias, (void*)out, 1, blockIdx.x & 3, blockIdx.x >> 2);
}

// ---------------- Flash attention: ab-split chains + q-doubling + XCD swizzle -----
// (R25 configuration — best measured: attn 44.5 us. Q pre-scaled by
// 0.125*log2e in the GEMM epilogue so softmax is exp2(s) directly.)
// Each wave: 64 q-rows x 1024 KV rows. Per KV subtile, FOUR independent short
// chains: (qA,ab0),(qB,ab0),(qA,ab1),(qB,ab1). No-max softmax; bid%8 == bh%8
// pins each head's blocks to one XCD (kF/vF L2-resident).
#define MAKE_PA(dst, p, ss) do {                                               \
    uint32_t w0_, w1_, w2_, w3_;                                               \
    asm("v_cvt_pk_bf16_f32 %0, %1, %2" : "=v"(w0_) : "v"(p[8*(ss)+0]), "v"(p[8*(ss)+1])); \
    asm("v_cvt_pk_bf16_f32 %0, %1, %2" : "=v"(w1_) : "v"(p[8*(ss)+2]), "v"(p[8*(ss)+3])); \
    asm("v_cvt_pk_bf16_f32 %0, %1, %2" : "=v"(w2_) : "v"(p[8*(ss)+4]), "v"(p[8*(ss)+5])); \
    asm("v_cvt_pk_bf16_f32 %0, %1, %2" : "=v"(w3_) : "v"(p[8*(ss)+6]), "v"(p[8*(ss)+7])); \
    asm("v_permlane32_swap_b32 %0, %1" : "+v"(w0_), "+v"(w2_));                \
    asm("v_permlane32_swap_b32 %0, %1" : "+v"(w1_), "+v"(w3_));                \
    union { uint32_t w[4]; bf16x8 v; } u_;                                     \
    u_.w[0] = w0_; u_.w[1] = w1_; u_.w[2] = w2_; u_.w[3] = w3_;                \
    dst = u_.v;                                                                \
} while (0)

#define KLOAD(DST, u) do {                                                     \
    const ushort* _p = kfb_ + (size_t)(u) * 4096 + lane * 8;                   \
    _Pragma("unroll")                                                          \
    for (int f_ = 0; f_ < 8; ++f_)                                             \
        DST[f_] = *reinterpret_cast<const bf16x8*>(_p + f_ * 512);             \
} while (0)

#define VLOAD(DST, u) do {                                                     \
    const ushort* _p = vfb_ + (size_t)((u) >> 1) * 8192 +                      \
                       ((u) & 1) * 4 * 512 + lane * 8;                         \
    _Pragma("unroll")                                                          \
    for (int hh_ = 0; hh_ < 2; ++hh_)                                          \
        _Pragma("unroll")                                                      \
        for (int s2_ = 0; s2_ < 4; ++s2_)                                      \
            DST[hh_ * 4 + s2_] = *reinterpret_cast<const bf16x8*>(             \
                _p + (hh_ * 8 + s2_) * 512);                                   \
} while (0)

// One 32-q-row x 32-kv-row chain (half AB of the current subtile).
#define COMPUTE_HALF(QF, OACC, LR, AB) do {                                    \
    f32x16 sS;                                                                 \
    _Pragma("unroll")                                                          \
    for (int j = 0; j < 16; ++j) sS[j] = 0.0f;                                 \
    __builtin_amdgcn_s_setprio(1);                                             \
    _Pragma("unroll")                                                          \
    for (int ds_ = 0; ds_ < 4; ++ds_)                                          \
        sS = __builtin_amdgcn_mfma_f32_32x32x16_bf16(kR[ds_ * 2 + (AB)], QF[ds_], sS, 0, 0, 0); \
    __builtin_amdgcn_s_setprio(0);                                             \
    float pf[16];                                                              \
    _Pragma("unroll")                                                          \
    for (int j = 0; j < 16; ++j)                                               \
        pf[j] = __builtin_amdgcn_exp2f(sS[j]);                                 \
    float r0 = 0.0f, r1 = 0.0f, r2 = 0.0f, r3 = 0.0f;                          \
    _Pragma("unroll")                                                          \
    for (int j = 0; j < 16; j += 4) {                                          \
        r0 += pf[j];     r1 += pf[j + 1];                                      \
        r2 += pf[j + 2]; r3 += pf[j + 3];                                      \
    }                                                                          \
    LR += (r0 + r1) + (r2 + r3);                                               \
    bf16x8 pa0, pa1;                                                           \
    MAKE_PA(pa0, pf, 0);                                                       \
    MAKE_PA(pa1, pf, 1);                                                       \
    __builtin_amdgcn_s_setprio(1);                                             \
    _Pragma("unroll")                                                          \
    for (int hh = 0; hh < 2; ++hh) {                                           \
        OACC[hh] = __builtin_amdgcn_mfma_f32_32x32x16_bf16(                    \
            pa0, vR[hh * 4 + (AB) * 2], OACC[hh], 0, 0, 0);                    \
        OACC[hh] = __builtin_amdgcn_mfma_f32_32x32x16_bf16(                    \
            pa1, vR[hh * 4 + (AB) * 2 + 1], OACC[hh], 0, 0, 0);                \
    }                                                                          \
    __builtin_amdgcn_s_setprio(0);                                             \
} while (0)

__global__ __launch_bounds__(512, 1) void attn_kernel(
    const ushort* __restrict__ q,   // [B*N][512] bf16 (pre-scaled)
    const ushort* __restrict__ kF,  // [H][16][16 frag][64 lane][8] bf16
    const ushort* __restrict__ vF,  // [B*H][16][16 frag][64 lane][8] bf16
    ushort* __restrict__ o)         // [B*N][512] bf16
{
    const int wave = threadIdx.x >> 6, lane = threadIdx.x & 63;
    const int l31 = lane & 31, g = lane >> 5;
    const int qpair = wave & 3, half = wave >> 2;
    const int bid = blockIdx.x;
    const int qx = bid >> 5, bh = bid & 31;   // bid%8 == bh%8 -> XCD pinning
    const int b = bh >> 3, h = bh & 7;
    const int q0 = qx * 256 + qpair * 64;     // rows q0..q0+63

    __shared__ float ols[4][64][64];   // 64 KB merge slots (one per q-pair)
    __shared__ float lls[4][2][64];    // 2 KB

    // Q fragments for both 32-row subtiles (hoisted)
    bf16x8 qfA[4], qfB[4];
    const ushort* qrowA = q + (size_t)(b * N_ + q0 + l31) * F_ + h * 64 + g * 8;
    const ushort* qrowB = qrowA + 32 * F_;
    #pragma unroll
    for (int ds = 0; ds < 4; ++ds) {
        qfA[ds] = *reinterpret_cast<const bf16x8*>(qrowA + ds * 16);
        qfB[ds] = *reinterpret_cast<const bf16x8*>(qrowB + ds * 16);
    }

    float l0 = 0.0f, l1 = 0.0f;
    f32x16 oaccA[2], oaccB[2];
    #pragma unroll
    for (int hh = 0; hh < 2; ++hh)
        #pragma unroll
        for (int j = 0; j < 16; ++j) { oaccA[hh][j] = 0.0f; oaccB[hh][j] = 0.0f; }

    const ushort* kfb_ = kF + (size_t)h * 16 * 16 * 512;
    const ushort* vfb_ = vF + (size_t)bh * 16 * 16 * 512;

    bf16x8 kR[8], vR[8];
    const int ubase = half * 16;         // this wave's 1024-row KV half

    #pragma unroll 1
    for (int uu = 0; uu < 16; ++uu) {
        int u = ubase + uu;
        KLOAD(kR, u);
        VLOAD(vR, u);
        COMPUTE_HALF(qfA, oaccA, l0, 0);
        COMPUTE_HALF(qfB, oaccB, l1, 0);
        COMPUTE_HALF(qfA, oaccA, l0, 1);
        COMPUTE_HALF(qfB, oaccB, l1, 1);
    }

    // partner-lane l merge
    l0 += __shfl_xor(l0, 32, 64);
    l1 += __shfl_xor(l1, 32, 64);

    // ---- pair merge: upper half publishes, lower half combines + stores ----------
    if (half) {
        #pragma unroll
        for (int hh = 0; hh < 2; ++hh)
            #pragma unroll
            for (int j = 0; j < 16; ++j) {
                ols[qpair][hh * 16 + j][lane] = oaccA[hh][j];
                ols[qpair][32 + hh * 16 + j][lane] = oaccB[hh][j];
            }
        lls[qpair][0][lane] = l0;
        lls[qpair][1][lane] = l1;
    }
    __syncthreads();
    if (!half) {
        #pragma unroll
        for (int hh = 0; hh < 2; ++hh)
            #pragma unroll
            for (int j = 0; j < 16; ++j) {
                oaccA[hh][j] += ols[qpair][hh * 16 + j][lane];
                oaccB[hh][j] += ols[qpair][32 + hh * 16 + j][lane];
            }
        l0 += lls[qpair][0][lane];
        l1 += lls[qpair][1][lane];
        float li0 = 1.0f / l0, li1 = 1.0f / l1;
        float rli0[16], rli1[16];
        #pragma unroll
        for (int j = 0; j < 16; ++j) {
            int idx = 8 * (j >> 2) + 4 * g + (j & 3);
            rli0[j] = __shfl(li0, idx, 64);
            rli1[j] = __shfl(li1, idx, 64);
        }
        #pragma unroll
        for (int hh = 0; hh < 2; ++hh)
            #pragma unroll
            for (int j = 0; j < 16; ++j) {
                int qr = (j & 3) + 8 * (j >> 2) + 4 * g;
                o[(size_t)(b * N_ + q0 + qr) * F_ + h * 64 + hh * 32 + l31] =
                    f32_bf16(oaccA[hh][j] * rli0[j]);
                o[(size_t)(b * N_ + q0 + 32 + qr) * F_ + h * 64 + hh * 32 + l31] =
                    f32_bf16(oaccB[hh][j] * rli1[j]);
            }
    }
}

// ---------------- Launch ---------------------------------------------------------
extern "C" void kernel_launch(void* const* d_in, const int* in_sizes, int n_in,
                              void* d_out, int out_size, void* d_ws, size_t ws_size,
                              hipStream_t stream) {
    const float* x    = (const float*)d_in[0];
    const float* ctx  = (const float*)d_in[1];
    const float* pos  = (const float*)d_in[2];
    const float* lnw  = (const float*)d_in[3];
    const float* lnb  = (const float*)d_in[4];
    const float* lncw = (const float*)d_in[5];
    const float* lncb = (const float*)d_in[6];
    const float* Wq   = (const float*)d_in[7];
    const float* Wk   = (const float*)d_in[8];
    const float* Wv   = (const float*)d_in[9];
    const float* Wo   = (const float*)d_in[10];
    const float* bout = (const float*)d_in[11];
    float* out = (float*)d_out;

    char* ws = (char*)d_ws;
    ushort* xn  = (ushort*)(ws + 0);         // 8 MB  [8192][512]
    ushort* cn  = (ushort*)(ws + 8388608);   // 8 MB  [8192][512]
    ushort* kn  = (ushort*)(ws + 16777216);  // 2 MB  [2048][512]
    ushort* WqT = (ushort*)(ws + 18874368);  // 512 KB
    ushort* WkT = (ushort*)(ws + 19398656);
    ushort* WvT = (ushort*)(ws + 19922944);
    ushort* WoT = (ushort*)(ws + 20447232);
    ushort* qb  = (ushort*)(ws + 20971520);  // 8 MB  [8192][512]
    ushort* kFb = (ushort*)(ws + 29360128);  // 2 MB  frag-packed K
    ushort* vFb = (ushort*)(ws + 39845888);  // 8 MB  frag-packed V
    ushort* ao  = (ushort*)(ws + 48234496);  // 8 MB  [8192][512]

    hipLaunchKernelGGL(prep_kernel, dim3(B_ * N_ + M_ + B_ * M_ + 1024), dim3(128),
                       0, stream,
                       x, ctx, pos, lnw, lnb, lncw, lncb, Wq, Wk, Wv, Wo,
                       xn, kn, cn, WqT, WkT, WvT, WoT);
    hipLaunchKernelGGL(qkv_gemm_kernel, dim3(576), dim3(256), 0, stream,
                       xn, kn, cn, WqT, WkT, WvT, qb, kFb, vFb);
    hipLaunchKernelGGL(attn_kernel, dim3(256), dim3(512), 0, stream,
                       qb, kFb, vFb, ao);
    hipLaunchKernelGGL(out_gemm_kernel, dim3(256), dim3(256), 0, stream,
                       ao, WoT, bout, out);
}

// Round 27
// 89.865 us; speedup vs baseline: 1.0585x; 1.0585x over previous
//
#include <hip/hip_runtime.h>
#include <stdint.h>

#define B_ 4
#define N_ 2048
#define M_ 2048
#define F_ 512
#define H_ 8
#define D_ 64

typedef __bf16 bf16x8 __attribute__((ext_vector_type(8)));
typedef float f32x4 __attribute__((ext_vector_type(4)));
typedef float f32x16 __attribute__((ext_vector_type(16)));

typedef const __attribute__((address_space(1))) uint32_t* gas_ptr;
typedef __attribute__((address_space(3))) uint32_t* las_ptr;

__device__ inline ushort f32_bf16(float f) {
    union { float f; uint32_t u; } v; v.f = f;
    uint32_t r = v.u + 0x7FFFu + ((v.u >> 16) & 1u);
    return (ushort)(r >> 16);
}

// ---------------- Fused LN (18432 rows) + weight transpose (1024 tile-blocks) -----
__global__ __launch_bounds__(128) void prep_kernel(
    const float* __restrict__ x, const float* __restrict__ ctx, const float* __restrict__ pos,
    const float* __restrict__ lnw, const float* __restrict__ lnb,
    const float* __restrict__ lncw, const float* __restrict__ lncb,
    const float* __restrict__ Wq, const float* __restrict__ Wk,
    const float* __restrict__ Wv, const float* __restrict__ Wo,
    ushort* __restrict__ xn, ushort* __restrict__ kn, ushort* __restrict__ cn,
    ushort* __restrict__ WqT, ushort* __restrict__ WkT,
    ushort* __restrict__ WvT, ushort* __restrict__ WoT)
{
    __shared__ float red[4];
    __shared__ float tile[32][33];
    int r = blockIdx.x;
    int tid = threadIdx.x;

    if (r < B_ * N_ + M_ + B_ * M_) {
        // ---- LayerNorm branch
        const float* src; ushort* dst; const float* w; const float* bp;
        if (r < B_ * N_) {
            src = x + (size_t)r * F_; dst = xn + (size_t)r * F_; w = lnw; bp = lnb;
        } else if (r < B_ * N_ + M_) {
            int rr = r - B_ * N_;
            src = pos + (size_t)rr * F_; dst = kn + (size_t)rr * F_; w = lnw; bp = lnb;
        } else {
            int rr = r - (B_ * N_ + M_);
            src = ctx + (size_t)rr * F_; dst = cn + (size_t)rr * F_; w = lncw; bp = lncb;
        }
        int wave = tid >> 6, lane = tid & 63;
        float4 v = reinterpret_cast<const float4*>(src)[tid];
        float s = v.x + v.y + v.z + v.w;
        float sq = v.x * v.x + v.y * v.y + v.z * v.z + v.w * v.w;
        #pragma unroll
        for (int mask = 1; mask < 64; mask <<= 1) {
            s += __shfl_xor(s, mask, 64);
            sq += __shfl_xor(sq, mask, 64);
        }
        if (lane == 0) { red[wave * 2] = s; red[wave * 2 + 1] = sq; }
        __syncthreads();
        float S = red[0] + red[2], SQ = red[1] + red[3];
        float mean = S * (1.0f / F_);
        float var = SQ * (1.0f / F_) - mean * mean;
        float rstd = rsqrtf(var + 1e-5f);
        float4 wv = reinterpret_cast<const float4*>(w)[tid];
        float4 bv = reinterpret_cast<const float4*>(bp)[tid];
        ushort4 o;
        o.x = f32_bf16((v.x - mean) * rstd * wv.x + bv.x);
        o.y = f32_bf16((v.y - mean) * rstd * wv.y + bv.y);
        o.z = f32_bf16((v.z - mean) * rstd * wv.z + bv.z);
        o.w = f32_bf16((v.w - mean) * rstd * wv.w + bv.w);
        reinterpret_cast<ushort4*>(dst)[tid] = o;
        return;
    }

    // ---- weight transpose branch: 1024 blocks of 32x32 tiles (128 threads)
    int wblk = r - (B_ * N_ + M_ + B_ * M_);
    const float* W; ushort* WT;
    switch (wblk >> 8) {
        case 0: W = Wq; WT = WqT; break;
        case 1: W = Wk; WT = WkT; break;
        case 2: W = Wv; WT = WvT; break;
        default: W = Wo; WT = WoT; break;
    }
    int ti = wblk & 255;
    int n0 = (ti & 15) * 32, k0 = (ti >> 4) * 32;
    int tx = tid & 31, ty = tid >> 5;          // 32 x 4
    #pragma unroll
    for (int j = 0; j < 8; ++j)
        tile[ty + j * 4][tx] = W[(size_t)(k0 + ty + j * 4) * F_ + n0 + tx];
    __syncthreads();
    #pragma unroll
    for (int j = 0; j < 8; ++j)
        WT[(size_t)(n0 + ty + j * 4) * F_ + k0 + tx] = f32_bf16(tile[tx][ty + j * 4]);
}

// ---------------- Shared GEMM body: global_load_lds + XOR-swizzled LDS ------------
// (R25 configuration — single-buffered; 32 KB LDS keeps 5 blocks/CU residency,
// which beats explicit 2-phase staging at 2 blocks/CU — measured R26.)
// mode: 0 = bf16 row-major PRE-SCALED by 0.125*log2e (Q projection),
//       1 = f32 row-major + bias,
//       2 = K fragment-pack (kF[h][t][fk][lane][8], fk=s*8+ds*2+ab),
//       3 = V fragment-pack (vF[bh][t][fv][lane][8], fv=hh*8+s*4+s_)
__device__ __forceinline__ void gemm_body(
    const ushort* __restrict__ A, const ushort* __restrict__ BT,
    const float* __restrict__ bias, void* __restrict__ Cout,
    int mode, int bx, int by)
{
    __shared__ ushort As[128][64];
    __shared__ ushort Bs[128][64];
    int tid = threadIdx.x;
    int row0 = by * 128, col0 = bx * 128;
    int wv = tid >> 6, lane = tid & 63;
    int wm = wv >> 1, wn = wv & 1;
    f32x4 acc[4][4] = {};

    const int lrow8 = lane >> 3;
    const int chs = ((lane & 7) ^ (lrow8 & 7)) * 8;
    const ushort* agp = A + (size_t)(row0 + wv * 32 + lrow8) * F_ + chs;
    const ushort* bgp = BT + (size_t)(col0 + wv * 32 + lrow8) * F_ + chs;

    for (int k0 = 0; k0 < F_; k0 += 64) {
        #pragma unroll
        for (int j = 0; j < 4; ++j) {
            __builtin_amdgcn_global_load_lds(
                (gas_ptr)(const void*)(agp + k0 + j * 8 * F_),
                (las_ptr)(void*)&As[wv * 32 + j * 8][0], 16, 0, 0);
            __builtin_amdgcn_global_load_lds(
                (gas_ptr)(const void*)(bgp + k0 + j * 8 * F_),
                (las_ptr)(void*)&Bs[wv * 32 + j * 8][0], 16, 0, 0);
        }
        __syncthreads();
        #pragma unroll
        for (int kt = 0; kt < 2; ++kt) {
            int lrow = lane & 15;
            int ch = ((kt * 4 + (lane >> 4)) ^ (lane & 7)) * 8;
            bf16x8 af[4], bfr[4];
            #pragma unroll
            for (int mt = 0; mt < 4; ++mt)
                af[mt] = *reinterpret_cast<const bf16x8*>(&As[wm * 64 + mt * 16 + lrow][ch]);
            #pragma unroll
            for (int nt = 0; nt < 4; ++nt)
                bfr[nt] = *reinterpret_cast<const bf16x8*>(&Bs[wn * 64 + nt * 16 + lrow][ch]);
            #pragma unroll
            for (int mt = 0; mt < 4; ++mt)
                #pragma unroll
                for (int nt = 0; nt < 4; ++nt)
                    acc[mt][nt] = __builtin_amdgcn_mfma_f32_16x16x32_bf16(
                        af[mt], bfr[nt], acc[mt][nt], 0, 0, 0);
        }
        __syncthreads();
    }

    int lr4 = (lane >> 4) * 4, lc = lane & 15;
    #pragma unroll
    for (int mt = 0; mt < 4; ++mt) {
        #pragma unroll
        for (int nt = 0; nt < 4; ++nt) {
            int ccol = col0 + wn * 64 + nt * 16 + lc;
            float bv = (mode == 1) ? bias[ccol] : 0.0f;
            #pragma unroll
            for (int j = 0; j < 4; ++j) {
                int crow = row0 + wm * 64 + mt * 16 + lr4 + j;
                float val = acc[mt][nt][j] + bv;
                if (mode == 1) {
                    reinterpret_cast<float*>(Cout)[(size_t)crow * F_ + ccol] = val;
                } else if (mode == 0) {
                    // fold softmax scale*log2(e) into Q at pack time
                    reinterpret_cast<ushort*>(Cout)[(size_t)crow * F_ + ccol] =
                        f32_bf16(val * 0.18033688f);
                } else if (mode == 2) {
                    int h = ccol >> 6, t = crow >> 7, s = (crow >> 6) & 1;
                    int ab = (crow >> 5) & 1, l31 = crow & 31;
                    int ds = (ccol >> 4) & 3, g2 = (ccol >> 3) & 1, e = ccol & 7;
                    size_t addr = (((size_t)(h * 16 + t) * 16 + s * 8 + ds * 2 + ab) * 64
                                   + g2 * 32 + l31) * 8 + e;
                    reinterpret_cast<ushort*>(Cout)[addr] = f32_bf16(val);
                } else {
                    int b2 = crow >> 11, m = crow & 2047;
                    int h = ccol >> 6, d = ccol & 63;
                    int bh = b2 * 8 + h, hh = d >> 5, l31 = d & 31;
                    int t = m >> 7, s = (m >> 6) & 1, s_ = (m >> 4) & 3;
                    int g2 = (m >> 3) & 1, i = m & 7;
                    size_t addr = (((size_t)(bh * 16 + t) * 16 + hh * 8 + s * 4 + s_) * 64
                                   + g2 * 32 + l31) * 8 + i;
                    reinterpret_cast<ushort*>(Cout)[addr] = f32_bf16(val);
                }
            }
        }
    }
}

// Merged Q/K/V projection: 576 blocks (Q:0-255, K:256-319, V:320-575).
__global__ __launch_bounds__(256) void qkv_gemm_kernel(
    const ushort* __restrict__ xn, const ushort* __restrict__ kn,
    const ushort* __restrict__ cn,
    const ushort* __restrict__ WqT, const ushort* __restrict__ WkT,
    const ushort* __restrict__ WvT,
    ushort* __restrict__ qb, ushort* __restrict__ kF, ushort* __restrict__ vF)
{
    int bid = blockIdx.x;
    if (bid < 256) {
        gemm_body(xn, WqT, nullptr, (void*)qb, 0, bid & 3, bid >> 2);
    } else if (bid < 320) {
        int t = bid - 256;
        gemm_body(kn, WkT, nullptr, (void*)kF, 2, t & 3, t >> 2);
    } else {
        int t = bid - 320;
        gemm_body(cn, WvT, nullptr, (void*)vF, 3, t & 3, t >> 2);
    }
}

__global__ __launch_bounds__(256) void out_gemm_kernel(
    const ushort* __restrict__ A, const ushort* __restrict__ WoT,
    const float* __restrict__ bias, float* __restrict__ out)
{
    gemm_body(A, WoT, bias, (void*)out, 1, blockIdx.x & 3, blockIdx.x >> 2);
}

// ---------------- Flash attention: ab-split chains + q-doubling + XCD swizzle -----
// (R25 configuration — best measured: attn 44.5 us, total 90.04 us. Q pre-scaled
// by 0.125*log2e in the GEMM epilogue so softmax is exp2(s) directly.)
// Each wave: 64 q-rows x 1024 KV rows. Per KV subtile, FOUR independent short
// chains: (qA,ab0),(qB,ab0),(qA,ab1),(qB,ab1). No-max softmax; bid%8 == bh%8
// pins each head's blocks to one XCD (kF/vF L2-resident).
#define MAKE_PA(dst, p, ss) do {                                               \
    uint32_t w0_, w1_, w2_, w3_;                                               \
    asm("v_cvt_pk_bf16_f32 %0, %1, %2" : "=v"(w0_) : "v"(p[8*(ss)+0]), "v"(p[8*(ss)+1])); \
    asm("v_cvt_pk_bf16_f32 %0, %1, %2" : "=v"(w1_) : "v"(p[8*(ss)+2]), "v"(p[8*(ss)+3])); \
    asm("v_cvt_pk_bf16_f32 %0, %1, %2" : "=v"(w2_) : "v"(p[8*(ss)+4]), "v"(p[8*(ss)+5])); \
    asm("v_cvt_pk_bf16_f32 %0, %1, %2" : "=v"(w3_) : "v"(p[8*(ss)+6]), "v"(p[8*(ss)+7])); \
    asm("v_permlane32_swap_b32 %0, %1" : "+v"(w0_), "+v"(w2_));                \
    asm("v_permlane32_swap_b32 %0, %1" : "+v"(w1_), "+v"(w3_));                \
    union { uint32_t w[4]; bf16x8 v; } u_;                                     \
    u_.w[0] = w0_; u_.w[1] = w1_; u_.w[2] = w2_; u_.w[3] = w3_;                \
    dst = u_.v;                                                                \
} while (0)

#define KLOAD(DST, u) do {                                                     \
    const ushort* _p = kfb_ + (size_t)(u) * 4096 + lane * 8;                   \
    _Pragma("unroll")                                                          \
    for (int f_ = 0; f_ < 8; ++f_)                                             \
        DST[f_] = *reinterpret_cast<const bf16x8*>(_p + f_ * 512);             \
} while (0)

#define VLOAD(DST, u) do {                                                     \
    const ushort* _p = vfb_ + (size_t)((u) >> 1) * 8192 +                      \
                       ((u) & 1) * 4 * 512 + lane * 8;                         \
    _Pragma("unroll")                                                          \
    for (int hh_ = 0; hh_ < 2; ++hh_)                                          \
        _Pragma("unroll")                                                      \
        for (int s2_ = 0; s2_ < 4; ++s2_)                                      \
            DST[hh_ * 4 + s2_] = *reinterpret_cast<const bf16x8*>(             \
                _p + (hh_ * 8 + s2_) * 512);                                   \
} while (0)

// One 32-q-row x 32-kv-row chain (half AB of the current subtile).
#define COMPUTE_HALF(QF, OACC, LR, AB) do {                                    \
    f32x16 sS;                                                                 \
    _Pragma("unroll")                                                          \
    for (int j = 0; j < 16; ++j) sS[j] = 0.0f;                                 \
    __builtin_amdgcn_s_setprio(1);                                             \
    _Pragma("unroll")                                                          \
    for (int ds_ = 0; ds_ < 4; ++ds_)                                          \
        sS = __builtin_amdgcn_mfma_f32_32x32x16_bf16(kR[ds_ * 2 + (AB)], QF[ds_], sS, 0, 0, 0); \
    __builtin_amdgcn_s_setprio(0);                                             \
    float pf[16];                                                              \
    _Pragma("unroll")                                                          \
    for (int j = 0; j < 16; ++j)                                               \
        pf[j] = __builtin_amdgcn_exp2f(sS[j]);                                 \
    float r0 = 0.0f, r1 = 0.0f, r2 = 0.0f, r3 = 0.0f;                          \
    _Pragma("unroll")                                                          \
    for (int j = 0; j < 16; j += 4) {                                          \
        r0 += pf[j];     r1 += pf[j + 1];                                      \
        r2 += pf[j + 2]; r3 += pf[j + 3];                                      \
    }                                                                          \
    LR += (r0 + r1) + (r2 + r3);                                               \
    bf16x8 pa0, pa1;                                                           \
    MAKE_PA(pa0, pf, 0);                                                       \
    MAKE_PA(pa1, pf, 1);                                                       \
    __builtin_amdgcn_s_setprio(1);                                             \
    _Pragma("unroll")                                                          \
    for (int hh = 0; hh < 2; ++hh) {                                           \
        OACC[hh] = __builtin_amdgcn_mfma_f32_32x32x16_bf16(                    \
            pa0, vR[hh * 4 + (AB) * 2], OACC[hh], 0, 0, 0);                    \
        OACC[hh] = __builtin_amdgcn_mfma_f32_32x32x16_bf16(                    \
            pa1, vR[hh * 4 + (AB) * 2 + 1], OACC[hh], 0, 0, 0);                \
    }                                                                          \
    __builtin_amdgcn_s_setprio(0);                                             \
} while (0)

__global__ __launch_bounds__(512, 1) void attn_kernel(
    const ushort* __restrict__ q,   // [B*N][512] bf16 (pre-scaled)
    const ushort* __restrict__ kF,  // [H][16][16 frag][64 lane][8] bf16
    const ushort* __restrict__ vF,  // [B*H][16][16 frag][64 lane][8] bf16
    ushort* __restrict__ o)         // [B*N][512] bf16
{
    const int wave = threadIdx.x >> 6, lane = threadIdx.x & 63;
    const int l31 = lane & 31, g = lane >> 5;
    const int qpair = wave & 3, half = wave >> 2;
    const int bid = blockIdx.x;
    const int qx = bid >> 5, bh = bid & 31;   // bid%8 == bh%8 -> XCD pinning
    const int b = bh >> 3, h = bh & 7;
    const int q0 = qx * 256 + qpair * 64;     // rows q0..q0+63

    __shared__ float ols[4][64][64];   // 64 KB merge slots (one per q-pair)
    __shared__ float lls[4][2][64];    // 2 KB

    // Q fragments for both 32-row subtiles (hoisted)
    bf16x8 qfA[4], qfB[4];
    const ushort* qrowA = q + (size_t)(b * N_ + q0 + l31) * F_ + h * 64 + g * 8;
    const ushort* qrowB = qrowA + 32 * F_;
    #pragma unroll
    for (int ds = 0; ds < 4; ++ds) {
        qfA[ds] = *reinterpret_cast<const bf16x8*>(qrowA + ds * 16);
        qfB[ds] = *reinterpret_cast<const bf16x8*>(qrowB + ds * 16);
    }

    float l0 = 0.0f, l1 = 0.0f;
    f32x16 oaccA[2], oaccB[2];
    #pragma unroll
    for (int hh = 0; hh < 2; ++hh)
        #pragma unroll
        for (int j = 0; j < 16; ++j) { oaccA[hh][j] = 0.0f; oaccB[hh][j] = 0.0f; }

    const ushort* kfb_ = kF + (size_t)h * 16 * 16 * 512;
    const ushort* vfb_ = vF + (size_t)bh * 16 * 16 * 512;

    bf16x8 kR[8], vR[8];
    const int ubase = half * 16;         // this wave's 1024-row KV half

    #pragma unroll 1
    for (int uu = 0; uu < 16; ++uu) {
        int u = ubase + uu;
        KLOAD(kR, u);
        VLOAD(vR, u);
        COMPUTE_HALF(qfA, oaccA, l0, 0);
        COMPUTE_HALF(qfB, oaccB, l1, 0);
        COMPUTE_HALF(qfA, oaccA, l0, 1);
        COMPUTE_HALF(qfB, oaccB, l1, 1);
    }

    // partner-lane l merge
    l0 += __shfl_xor(l0, 32, 64);
    l1 += __shfl_xor(l1, 32, 64);

    // ---- pair merge: upper half publishes, lower half combines + stores ----------
    if (half) {
        #pragma unroll
        for (int hh = 0; hh < 2; ++hh)
            #pragma unroll
            for (int j = 0; j < 16; ++j) {
                ols[qpair][hh * 16 + j][lane] = oaccA[hh][j];
                ols[qpair][32 + hh * 16 + j][lane] = oaccB[hh][j];
            }
        lls[qpair][0][lane] = l0;
        lls[qpair][1][lane] = l1;
    }
    __syncthreads();
    if (!half) {
        #pragma unroll
        for (int hh = 0; hh < 2; ++hh)
            #pragma unroll
            for (int j = 0; j < 16; ++j) {
                oaccA[hh][j] += ols[qpair][hh * 16 + j][lane];
                oaccB[hh][j] += ols[qpair][32 + hh * 16 + j][lane];
            }
        l0 += lls[qpair][0][lane];
        l1 += lls[qpair][1][lane];
        float li0 = 1.0f / l0, li1 = 1.0f / l1;
        float rli0[16], rli1[16];
        #pragma unroll
        for (int j = 0; j < 16; ++j) {
            int idx = 8 * (j >> 2) + 4 * g + (j & 3);
            rli0[j] = __shfl(li0, idx, 64);
            rli1[j] = __shfl(li1, idx, 64);
        }
        #pragma unroll
        for (int hh = 0; hh < 2; ++hh)
            #pragma unroll
            for (int j = 0; j < 16; ++j) {
                int qr = (j & 3) + 8 * (j >> 2) + 4 * g;
                o[(size_t)(b * N_ + q0 + qr) * F_ + h * 64 + hh * 32 + l31] =
                    f32_bf16(oaccA[hh][j] * rli0[j]);
                o[(size_t)(b * N_ + q0 + 32 + qr) * F_ + h * 64 + hh * 32 + l31] =
                    f32_bf16(oaccB[hh][j] * rli1[j]);
            }
    }
}

// ---------------- Launch ---------------------------------------------------------
extern "C" void kernel_launch(void* const* d_in, const int* in_sizes, int n_in,
                              void* d_out, int out_size, void* d_ws, size_t ws_size,
                              hipStream_t stream) {
    const float* x    = (const float*)d_in[0];
    const float* ctx  = (const float*)d_in[1];
    const float* pos  = (const float*)d_in[2];
    const float* lnw  = (const float*)d_in[3];
    const float* lnb  = (const float*)d_in[4];
    const float* lncw = (const float*)d_in[5];
    const float* lncb = (const float*)d_in[6];
    const float* Wq   = (const float*)d_in[7];
    const float* Wk   = (const float*)d_in[8];
    const float* Wv   = (const float*)d_in[9];
    const float* Wo   = (const float*)d_in[10];
    const float* bout = (const float*)d_in[11];
    float* out = (float*)d_out;

    char* ws = (char*)d_ws;
    ushort* xn  = (ushort*)(ws + 0);         // 8 MB  [8192][512]
    ushort* cn  = (ushort*)(ws + 8388608);   // 8 MB  [8192][512]
    ushort* kn  = (ushort*)(ws + 16777216);  // 2 MB  [2048][512]
    ushort* WqT = (ushort*)(ws + 18874368);  // 512 KB
    ushort* WkT = (ushort*)(ws + 19398656);
    ushort* WvT = (ushort*)(ws + 19922944);
    ushort* WoT = (ushort*)(ws + 20447232);
    ushort* qb  = (ushort*)(ws + 20971520);  // 8 MB  [8192][512]
    ushort* kFb = (ushort*)(ws + 29360128);  // 2 MB  frag-packed K
    ushort* vFb = (ushort*)(ws + 39845888);  // 8 MB  frag-packed V
    ushort* ao  = (ushort*)(ws + 48234496);  // 8 MB  [8192][512]

    hipLaunchKernelGGL(prep_kernel, dim3(B_ * N_ + M_ + B_ * M_ + 1024), dim3(128),
                       0, stream,
                       x, ctx, pos, lnw, lnb, lncw, lncb, Wq, Wk, Wv, Wo,
                       xn, kn, cn, WqT, WkT, WvT, WoT);
    hipLaunchKernelGGL(qkv_gemm_kernel, dim3(576), dim3(256), 0, stream,
                       xn, kn, cn, WqT, WkT, WvT, qb, kFb, vFb);
    hipLaunchKernelGGL(attn_kernel, dim3(256), dim3(512), 0, stream,
                       qb, kFb, vFb, ao);
    hipLaunchKernelGGL(out_gemm_kernel, dim3(256), dim3(256), 0, stream,
                       ao, WoT, bout, out);
}

// Round 28
// 89.507 us; speedup vs baseline: 1.0627x; 1.0040x over previous
//
#include <hip/hip_runtime.h>
#include <stdint.h>

#define B_ 4
#define N_ 2048
#define M_ 2048
#define F_ 512
#define H_ 8
#define D_ 64

typedef __bf16 bf16x8 __attribute__((ext_vector_type(8)));
typedef float f32x4 __attribute__((ext_vector_type(4)));
typedef float f32x16 __attribute__((ext_vector_type(16)));

typedef const __attribute__((address_space(1))) uint32_t* gas_ptr;
typedef __attribute__((address_space(3))) uint32_t* las_ptr;

__device__ inline ushort f32_bf16(float f) {
    union { float f; uint32_t u; } v; v.f = f;
    uint32_t r = v.u + 0x7FFFu + ((v.u >> 16) & 1u);
    return (ushort)(r >> 16);
}

// ---------------- Fused LN (18432 rows) + weight transpose (1024 tile-blocks) -----
__global__ __launch_bounds__(128) void prep_kernel(
    const float* __restrict__ x, const float* __restrict__ ctx, const float* __restrict__ pos,
    const float* __restrict__ lnw, const float* __restrict__ lnb,
    const float* __restrict__ lncw, const float* __restrict__ lncb,
    const float* __restrict__ Wq, const float* __restrict__ Wk,
    const float* __restrict__ Wv, const float* __restrict__ Wo,
    ushort* __restrict__ xn, ushort* __restrict__ kn, ushort* __restrict__ cn,
    ushort* __restrict__ WqT, ushort* __restrict__ WkT,
    ushort* __restrict__ WvT, ushort* __restrict__ WoT)
{
    __shared__ float red[4];
    __shared__ float tile[32][33];
    int r = blockIdx.x;
    int tid = threadIdx.x;

    if (r < B_ * N_ + M_ + B_ * M_) {
        // ---- LayerNorm branch
        const float* src; ushort* dst; const float* w; const float* bp;
        if (r < B_ * N_) {
            src = x + (size_t)r * F_; dst = xn + (size_t)r * F_; w = lnw; bp = lnb;
        } else if (r < B_ * N_ + M_) {
            int rr = r - B_ * N_;
            src = pos + (size_t)rr * F_; dst = kn + (size_t)rr * F_; w = lnw; bp = lnb;
        } else {
            int rr = r - (B_ * N_ + M_);
            src = ctx + (size_t)rr * F_; dst = cn + (size_t)rr * F_; w = lncw; bp = lncb;
        }
        int wave = tid >> 6, lane = tid & 63;
        float4 v = reinterpret_cast<const float4*>(src)[tid];
        float s = v.x + v.y + v.z + v.w;
        float sq = v.x * v.x + v.y * v.y + v.z * v.z + v.w * v.w;
        #pragma unroll
        for (int mask = 1; mask < 64; mask <<= 1) {
            s += __shfl_xor(s, mask, 64);
            sq += __shfl_xor(sq, mask, 64);
        }
        if (lane == 0) { red[wave * 2] = s; red[wave * 2 + 1] = sq; }
        __syncthreads();
        float S = red[0] + red[2], SQ = red[1] + red[3];
        float mean = S * (1.0f / F_);
        float var = SQ * (1.0f / F_) - mean * mean;
        float rstd = rsqrtf(var + 1e-5f);
        float4 wv = reinterpret_cast<const float4*>(w)[tid];
        float4 bv = reinterpret_cast<const float4*>(bp)[tid];
        ushort4 o;
        o.x = f32_bf16((v.x - mean) * rstd * wv.x + bv.x);
        o.y = f32_bf16((v.y - mean) * rstd * wv.y + bv.y);
        o.z = f32_bf16((v.z - mean) * rstd * wv.z + bv.z);
        o.w = f32_bf16((v.w - mean) * rstd * wv.w + bv.w);
        reinterpret_cast<ushort4*>(dst)[tid] = o;
        return;
    }

    // ---- weight transpose branch: 1024 blocks of 32x32 tiles (128 threads)
    int wblk = r - (B_ * N_ + M_ + B_ * M_);
    const float* W; ushort* WT;
    switch (wblk >> 8) {
        case 0: W = Wq; WT = WqT; break;
        case 1: W = Wk; WT = WkT; break;
        case 2: W = Wv; WT = WvT; break;
        default: W = Wo; WT = WoT; break;
    }
    int ti = wblk & 255;
    int n0 = (ti & 15) * 32, k0 = (ti >> 4) * 32;
    int tx = tid & 31, ty = tid >> 5;          // 32 x 4
    #pragma unroll
    for (int j = 0; j < 8; ++j)
        tile[ty + j * 4][tx] = W[(size_t)(k0 + ty + j * 4) * F_ + n0 + tx];
    __syncthreads();
    #pragma unroll
    for (int j = 0; j < 8; ++j)
        WT[(size_t)(n0 + ty + j * 4) * F_ + k0 + tx] = f32_bf16(tile[tx][ty + j * 4]);
}

// ---------------- Shared GEMM body: global_load_lds + XOR-swizzled LDS ------------
// (Single-buffered; 32 KB LDS keeps 5 blocks/CU residency — beats explicit
// 2-phase staging at 2 blocks/CU, measured R26.)
// mode: 0 = bf16 row-major PRE-SCALED by 0.125*log2e (Q projection),
//       1 = f32 row-major + bias,
//       2 = K fragment-pack (kF[h][t][fk][lane][8], fk=s*8+ds*2+ab),
//       3 = V fragment-pack (vF[bh][t][fv][lane][8], fv=hh*8+s*4+s_) —
//           j=0..3 values are consecutive elements i=(lr4+j)&7 with all higher
//           addr bits j-invariant, merged into ONE 8B store (was 4x 2B scatter).
__device__ __forceinline__ void gemm_body(
    const ushort* __restrict__ A, const ushort* __restrict__ BT,
    const float* __restrict__ bias, void* __restrict__ Cout,
    int mode, int bx, int by)
{
    __shared__ ushort As[128][64];
    __shared__ ushort Bs[128][64];
    int tid = threadIdx.x;
    int row0 = by * 128, col0 = bx * 128;
    int wv = tid >> 6, lane = tid & 63;
    int wm = wv >> 1, wn = wv & 1;
    f32x4 acc[4][4] = {};

    const int lrow8 = lane >> 3;
    const int chs = ((lane & 7) ^ (lrow8 & 7)) * 8;
    const ushort* agp = A + (size_t)(row0 + wv * 32 + lrow8) * F_ + chs;
    const ushort* bgp = BT + (size_t)(col0 + wv * 32 + lrow8) * F_ + chs;

    for (int k0 = 0; k0 < F_; k0 += 64) {
        #pragma unroll
        for (int j = 0; j < 4; ++j) {
            __builtin_amdgcn_global_load_lds(
                (gas_ptr)(const void*)(agp + k0 + j * 8 * F_),
                (las_ptr)(void*)&As[wv * 32 + j * 8][0], 16, 0, 0);
            __builtin_amdgcn_global_load_lds(
                (gas_ptr)(const void*)(bgp + k0 + j * 8 * F_),
                (las_ptr)(void*)&Bs[wv * 32 + j * 8][0], 16, 0, 0);
        }
        __syncthreads();
        #pragma unroll
        for (int kt = 0; kt < 2; ++kt) {
            int lrow = lane & 15;
            int ch = ((kt * 4 + (lane >> 4)) ^ (lane & 7)) * 8;
            bf16x8 af[4], bfr[4];
            #pragma unroll
            for (int mt = 0; mt < 4; ++mt)
                af[mt] = *reinterpret_cast<const bf16x8*>(&As[wm * 64 + mt * 16 + lrow][ch]);
            #pragma unroll
            for (int nt = 0; nt < 4; ++nt)
                bfr[nt] = *reinterpret_cast<const bf16x8*>(&Bs[wn * 64 + nt * 16 + lrow][ch]);
            #pragma unroll
            for (int mt = 0; mt < 4; ++mt)
                #pragma unroll
                for (int nt = 0; nt < 4; ++nt)
                    acc[mt][nt] = __builtin_amdgcn_mfma_f32_16x16x32_bf16(
                        af[mt], bfr[nt], acc[mt][nt], 0, 0, 0);
        }
        __syncthreads();
    }

    int lr4 = (lane >> 4) * 4, lc = lane & 15;
    #pragma unroll
    for (int mt = 0; mt < 4; ++mt) {
        #pragma unroll
        for (int nt = 0; nt < 4; ++nt) {
            int ccol = col0 + wn * 64 + nt * 16 + lc;
            float bv = (mode == 1) ? bias[ccol] : 0.0f;
            if (mode == 3) {
                // merged 8B store: 4 consecutive bf16 elems (i = (lr4+j)&7)
                int crow0 = row0 + wm * 64 + mt * 16 + lr4;
                int b2 = crow0 >> 11, m = crow0 & 2047;
                int h = ccol >> 6, d = ccol & 63;
                int bh = b2 * 8 + h, hh = d >> 5, l31 = d & 31;
                int t = m >> 7, s = (m >> 6) & 1, s_ = (m >> 4) & 3;
                int g2 = (m >> 3) & 1, i0 = m & 7;
                size_t addr = (((size_t)(bh * 16 + t) * 16 + hh * 8 + s * 4 + s_) * 64
                               + g2 * 32 + l31) * 8 + i0;
                union { ushort u[4]; uint2 q; } pk;
                #pragma unroll
                for (int j = 0; j < 4; ++j) pk.u[j] = f32_bf16(acc[mt][nt][j]);
                *reinterpret_cast<uint2*>(&reinterpret_cast<ushort*>(Cout)[addr]) = pk.q;
                continue;
            }
            #pragma unroll
            for (int j = 0; j < 4; ++j) {
                int crow = row0 + wm * 64 + mt * 16 + lr4 + j;
                float val = acc[mt][nt][j] + bv;
                if (mode == 1) {
                    reinterpret_cast<float*>(Cout)[(size_t)crow * F_ + ccol] = val;
                } else if (mode == 0) {
                    // fold softmax scale*log2(e) into Q at pack time
                    reinterpret_cast<ushort*>(Cout)[(size_t)crow * F_ + ccol] =
                        f32_bf16(val * 0.18033688f);
                } else {  // mode == 2
                    int h = ccol >> 6, t = crow >> 7, s = (crow >> 6) & 1;
                    int ab = (crow >> 5) & 1, l31 = crow & 31;
                    int ds = (ccol >> 4) & 3, g2 = (ccol >> 3) & 1, e = ccol & 7;
                    size_t addr = (((size_t)(h * 16 + t) * 16 + s * 8 + ds * 2 + ab) * 64
                                   + g2 * 32 + l31) * 8 + e;
                    reinterpret_cast<ushort*>(Cout)[addr] = f32_bf16(val);
                }
            }
        }
    }
}

// Merged Q/K/V projection: 576 blocks (Q:0-255, K:256-319, V:320-575).
__global__ __launch_bounds__(256) void qkv_gemm_kernel(
    const ushort* __restrict__ xn, const ushort* __restrict__ kn,
    const ushort* __restrict__ cn,
    const ushort* __restrict__ WqT, const ushort* __restrict__ WkT,
    const ushort* __restrict__ WvT,
    ushort* __restrict__ qb, ushort* __restrict__ kF, ushort* __restrict__ vF)
{
    int bid = blockIdx.x;
    if (bid < 256) {
        gemm_body(xn, WqT, nullptr, (void*)qb, 0, bid & 3, bid >> 2);
    } else if (bid < 320) {
        int t = bid - 256;
        gemm_body(kn, WkT, nullptr, (void*)kF, 2, t & 3, t >> 2);
    } else {
        int t = bid - 320;
        gemm_body(cn, WvT, nullptr, (void*)vF, 3, t & 3, t >> 2);
    }
}

__global__ __launch_bounds__(256) void out_gemm_kernel(
    const ushort* __restrict__ A, const ushort* __restrict__ WoT,
    const float* __restrict__ bias, float* __restrict__ out)
{
    gemm_body(A, WoT, bias, (void*)out, 1, blockIdx.x & 3, blockIdx.x >> 2);
}

// ---------------- Flash attention: ab-split chains + q-doubling + XCD swizzle -----
// (Best measured: attn 44.5 us, total 89.9 us. Q pre-scaled by 0.125*log2e in
// the GEMM epilogue so softmax is exp2(s) directly.)
// Each wave: 64 q-rows x 1024 KV rows. Per KV subtile, FOUR independent short
// chains: (qA,ab0),(qB,ab0),(qA,ab1),(qB,ab1). No-max softmax; bid%8 == bh%8
// pins each head's blocks to one XCD (kF/vF L2-resident).
#define MAKE_PA(dst, p, ss) do {                                               \
    uint32_t w0_, w1_, w2_, w3_;                                               \
    asm("v_cvt_pk_bf16_f32 %0, %1, %2" : "=v"(w0_) : "v"(p[8*(ss)+0]), "v"(p[8*(ss)+1])); \
    asm("v_cvt_pk_bf16_f32 %0, %1, %2" : "=v"(w1_) : "v"(p[8*(ss)+2]), "v"(p[8*(ss)+3])); \
    asm("v_cvt_pk_bf16_f32 %0, %1, %2" : "=v"(w2_) : "v"(p[8*(ss)+4]), "v"(p[8*(ss)+5])); \
    asm("v_cvt_pk_bf16_f32 %0, %1, %2" : "=v"(w3_) : "v"(p[8*(ss)+6]), "v"(p[8*(ss)+7])); \
    asm("v_permlane32_swap_b32 %0, %1" : "+v"(w0_), "+v"(w2_));                \
    asm("v_permlane32_swap_b32 %0, %1" : "+v"(w1_), "+v"(w3_));                \
    union { uint32_t w[4]; bf16x8 v; } u_;                                     \
    u_.w[0] = w0_; u_.w[1] = w1_; u_.w[2] = w2_; u_.w[3] = w3_;                \
    dst = u_.v;                                                                \
} while (0)

#define KLOAD(DST, u) do {                                                     \
    const ushort* _p = kfb_ + (size_t)(u) * 4096 + lane * 8;                   \
    _Pragma("unroll")                                                          \
    for (int f_ = 0; f_ < 8; ++f_)                                             \
        DST[f_] = *reinterpret_cast<const bf16x8*>(_p + f_ * 512);             \
} while (0)

#define VLOAD(DST, u) do {                                                     \
    const ushort* _p = vfb_ + (size_t)((u) >> 1) * 8192 +                      \
                       ((u) & 1) * 4 * 512 + lane * 8;                         \
    _Pragma("unroll")                                                          \
    for (int hh_ = 0; hh_ < 2; ++hh_)                                          \
        _Pragma("unroll")                                                      \
        for (int s2_ = 0; s2_ < 4; ++s2_)                                      \
            DST[hh_ * 4 + s2_] = *reinterpret_cast<const bf16x8*>(             \
                _p + (hh_ * 8 + s2_) * 512);                                   \
} while (0)

// One 32-q-row x 32-kv-row chain (half AB of the current subtile).
#define COMPUTE_HALF(QF, OACC, LR, AB) do {                                    \
    f32x16 sS;                                                                 \
    _Pragma("unroll")                                                          \
    for (int j = 0; j < 16; ++j) sS[j] = 0.0f;                                 \
    __builtin_amdgcn_s_setprio(1);                                             \
    _Pragma("unroll")                                                          \
    for (int ds_ = 0; ds_ < 4; ++ds_)                                          \
        sS = __builtin_amdgcn_mfma_f32_32x32x16_bf16(kR[ds_ * 2 + (AB)], QF[ds_], sS, 0, 0, 0); \
    __builtin_amdgcn_s_setprio(0);                                             \
    float pf[16];                                                              \
    _Pragma("unroll")                                                          \
    for (int j = 0; j < 16; ++j)                                               \
        pf[j] = __builtin_amdgcn_exp2f(sS[j]);                                 \
    float r0 = 0.0f, r1 = 0.0f, r2 = 0.0f, r3 = 0.0f;                          \
    _Pragma("unroll")                                                          \
    for (int j = 0; j < 16; j += 4) {                                          \
        r0 += pf[j];     r1 += pf[j + 1];                                      \
        r2 += pf[j + 2]; r3 += pf[j + 3];                                      \
    }                                                                          \
    LR += (r0 + r1) + (r2 + r3);                                               \
    bf16x8 pa0, pa1;                                                           \
    MAKE_PA(pa0, pf, 0);                                                       \
    MAKE_PA(pa1, pf, 1);                                                       \
    __builtin_amdgcn_s_setprio(1);                                             \
    _Pragma("unroll")                                                          \
    for (int hh = 0; hh < 2; ++hh) {                                           \
        OACC[hh] = __builtin_amdgcn_mfma_f32_32x32x16_bf16(                    \
            pa0, vR[hh * 4 + (AB) * 2], OACC[hh], 0, 0, 0);                    \
        OACC[hh] = __builtin_amdgcn_mfma_f32_32x32x16_bf16(                    \
            pa1, vR[hh * 4 + (AB) * 2 + 1], OACC[hh], 0, 0, 0);                \
    }                                                                          \
    __builtin_amdgcn_s_setprio(0);                                             \
} while (0)

__global__ __launch_bounds__(512, 1) void attn_kernel(
    const ushort* __restrict__ q,   // [B*N][512] bf16 (pre-scaled)
    const ushort* __restrict__ kF,  // [H][16][16 frag][64 lane][8] bf16
    const ushort* __restrict__ vF,  // [B*H][16][16 frag][64 lane][8] bf16
    ushort* __restrict__ o)         // [B*N][512] bf16
{
    const int wave = threadIdx.x >> 6, lane = threadIdx.x & 63;
    const int l31 = lane & 31, g = lane >> 5;
    const int qpair = wave & 3, half = wave >> 2;
    const int bid = blockIdx.x;
    const int qx = bid >> 5, bh = bid & 31;   // bid%8 == bh%8 -> XCD pinning
    const int b = bh >> 3, h = bh & 7;
    const int q0 = qx * 256 + qpair * 64;     // rows q0..q0+63

    __shared__ float ols[4][64][64];   // 64 KB merge slots (one per q-pair)
    __shared__ float lls[4][2][64];    // 2 KB

    // Q fragments for both 32-row subtiles (hoisted)
    bf16x8 qfA[4], qfB[4];
    const ushort* qrowA = q + (size_t)(b * N_ + q0 + l31) * F_ + h * 64 + g * 8;
    const ushort* qrowB = qrowA + 32 * F_;
    #pragma unroll
    for (int ds = 0; ds < 4; ++ds) {
        qfA[ds] = *reinterpret_cast<const bf16x8*>(qrowA + ds * 16);
        qfB[ds] = *reinterpret_cast<const bf16x8*>(qrowB + ds * 16);
    }

    float l0 = 0.0f, l1 = 0.0f;
    f32x16 oaccA[2], oaccB[2];
    #pragma unroll
    for (int hh = 0; hh < 2; ++hh)
        #pragma unroll
        for (int j = 0; j < 16; ++j) { oaccA[hh][j] = 0.0f; oaccB[hh][j] = 0.0f; }

    const ushort* kfb_ = kF + (size_t)h * 16 * 16 * 512;
    const ushort* vfb_ = vF + (size_t)bh * 16 * 16 * 512;

    bf16x8 kR[8], vR[8];
    const int ubase = half * 16;         // this wave's 1024-row KV half

    #pragma unroll 1
    for (int uu = 0; uu < 16; ++uu) {
        int u = ubase + uu;
        KLOAD(kR, u);
        VLOAD(vR, u);
        COMPUTE_HALF(qfA, oaccA, l0, 0);
        COMPUTE_HALF(qfB, oaccB, l1, 0);
        COMPUTE_HALF(qfA, oaccA, l0, 1);
        COMPUTE_HALF(qfB, oaccB, l1, 1);
    }

    // partner-lane l merge
    l0 += __shfl_xor(l0, 32, 64);
    l1 += __shfl_xor(l1, 32, 64);

    // ---- pair merge: upper half publishes, lower half combines + stores ----------
    if (half) {
        #pragma unroll
        for (int hh = 0; hh < 2; ++hh)
            #pragma unroll
            for (int j = 0; j < 16; ++j) {
                ols[qpair][hh * 16 + j][lane] = oaccA[hh][j];
                ols[qpair][32 + hh * 16 + j][lane] = oaccB[hh][j];
            }
        lls[qpair][0][lane] = l0;
        lls[qpair][1][lane] = l1;
    }
    __syncthreads();
    if (!half) {
        #pragma unroll
        for (int hh = 0; hh < 2; ++hh)
            #pragma unroll
            for (int j = 0; j < 16; ++j) {
                oaccA[hh][j] += ols[qpair][hh * 16 + j][lane];
                oaccB[hh][j] += ols[qpair][32 + hh * 16 + j][lane];
            }
        l0 += lls[qpair][0][lane];
        l1 += lls[qpair][1][lane];
        float li0 = 1.0f / l0, li1 = 1.0f / l1;
        float rli0[16], rli1[16];
        #pragma unroll
        for (int j = 0; j < 16; ++j) {
            int idx = 8 * (j >> 2) + 4 * g + (j & 3);
            rli0[j] = __shfl(li0, idx, 64);
            rli1[j] = __shfl(li1, idx, 64);
        }
        #pragma unroll
        for (int hh = 0; hh < 2; ++hh)
            #pragma unroll
            for (int j = 0; j < 16; ++j) {
                int qr = (j & 3) + 8 * (j >> 2) + 4 * g;
                o[(size_t)(b * N_ + q0 + qr) * F_ + h * 64 + hh * 32 + l31] =
                    f32_bf16(oaccA[hh][j] * rli0[j]);
                o[(size_t)(b * N_ + q0 + 32 + qr) * F_ + h * 64 + hh * 32 + l31] =
                    f32_bf16(oaccB[hh][j] * rli1[j]);
            }
    }
}

// ---------------- Launch ---------------------------------------------------------
extern "C" void kernel_launch(void* const* d_in, const int* in_sizes, int n_in,
                              void* d_out, int out_size, void* d_ws, size_t ws_size,
                              hipStream_t stream) {
    const float* x    = (const float*)d_in[0];
    const float* ctx  = (const float*)d_in[1];
    const float* pos  = (const float*)d_in[2];
    const float* lnw  = (const float*)d_in[3];
    const float* lnb  = (const float*)d_in[4];
    const float* lncw = (const float*)d_in[5];
    const float* lncb = (const float*)d_in[6];
    const float* Wq   = (const float*)d_in[7];
    const float* Wk   = (const float*)d_in[8];
    const float* Wv   = (const float*)d_in[9];
    const float* Wo   = (const float*)d_in[10];
    const float* bout = (const float*)d_in[11];
    float* out = (float*)d_out;

    char* ws = (char*)d_ws;
    ushort* xn  = (ushort*)(ws + 0);         // 8 MB  [8192][512]
    ushort* cn  = (ushort*)(ws + 8388608);   // 8 MB  [8192][512]
    ushort* kn  = (ushort*)(ws + 16777216);  // 2 MB  [2048][512]
    ushort* WqT = (ushort*)(ws + 18874368);  // 512 KB
    ushort* WkT = (ushort*)(ws + 19398656);
    ushort* WvT = (ushort*)(ws + 19922944);
    ushort* WoT = (ushort*)(ws + 20447232);
    ushort* qb  = (ushort*)(ws + 20971520);  // 8 MB  [8192][512]
    ushort* kFb = (ushort*)(ws + 29360128);  // 2 MB  frag-packed K
    ushort* vFb = (ushort*)(ws + 39845888);  // 8 MB  frag-packed V
    ushort* ao  = (ushort*)(ws + 48234496);  // 8 MB  [8192][512]

    hipLaunchKernelGGL(prep_kernel, dim3(B_ * N_ + M_ + B_ * M_ + 1024), dim3(128),
                       0, stream,
                       x, ctx, pos, lnw, lnb, lncw, lncb, Wq, Wk, Wv, Wo,
                       xn, kn, cn, WqT, WkT, WvT, WoT);
    hipLaunchKernelGGL(qkv_gemm_kernel, dim3(576), dim3(256), 0, stream,
                       xn, kn, cn, WqT, WkT, WvT, qb, kFb, vFb);
    hipLaunchKernelGGL(attn_kernel, dim3(256), dim3(512), 0, stream,
                       qb, kFb, vFb, ao);
    hipLaunchKernelGGL(out_gemm_kernel, dim3(256), dim3(256), 0, stream,
                       ao, WoT, bout, out);
}